// Round 6
// baseline (872.125 us; speedup 1.0000x reference)
//
#include <hip/hip_runtime.h>

// Problem constants
#define B_  8192
#define L_  10
#define D_  128
#define H_  64
#define OUT_ 5

// ws float layout (all fp32):
#define WS_ENCW4   0                    // 192*256: [k][l][q] = encW[j=q*64+l][k]  (k<128: Wih, else Whh)
#define WS_ENCB4   49152                // 256:     [l][q] = bih[j]+bhh[j]
#define WS_DECW4   49408                // 69*256:  [k][l][q] = decW[j][k] (k<5: Wih, else Whh)
#define WS_DECB4   67072                // 256
#define WS_W1HC2   67328                // 64*64*2: [e][l][{W1h[l][e], W1c[l][e]}]
#define WS_W1XT    75520                // 64*64:   [e][l] = W1x[l][e]

__device__ __forceinline__ float sigmf(float x){ return 1.f/(1.f+__expf(-x)); }
__device__ __forceinline__ float tanhf_(float x){ return 1.f - 2.f/(1.f+__expf(2.f*x)); }
__device__ __forceinline__ float bcast(float v, int lane){
  return __uint_as_float(__builtin_amdgcn_readlane(__float_as_uint(v), lane));
}

__global__ void prep_kernel(const float* __restrict__ encWih, const float* __restrict__ encWhh,
                            const float* __restrict__ encbih, const float* __restrict__ encbhh,
                            const float* __restrict__ decWih, const float* __restrict__ decWhh,
                            const float* __restrict__ decbih, const float* __restrict__ decbhh,
                            const float* __restrict__ w1, float* __restrict__ ws)
{
  int stride = gridDim.x * blockDim.x;
  int tid0 = blockIdx.x * blockDim.x + threadIdx.x;
  for (int idx = tid0; idx < 192*256; idx += stride) {
    int k = idx >> 8, r = idx & 255, l = r >> 2, q = r & 3;
    int j = q*64 + l;
    float v = (k < 128) ? encWih[j*128 + k] : encWhh[j*64 + (k-128)];
    ws[WS_ENCW4 + idx] = v;
  }
  for (int idx = tid0; idx < 256; idx += stride) {
    int l = idx >> 2, q = idx & 3, j = q*64+l;
    ws[WS_ENCB4+idx] = encbih[j] + encbhh[j];
  }
  for (int idx = tid0; idx < 69*256; idx += stride) {
    int k = idx >> 8, r = idx & 255, l = r >> 2, q = r & 3, j = q*64+l;
    float v = (k < 5) ? decWih[j*5 + k] : decWhh[j*64 + (k-5)];
    ws[WS_DECW4 + idx] = v;
  }
  for (int idx = tid0; idx < 256; idx += stride) {
    int l = idx >> 2, q = idx & 3, j = q*64+l;
    ws[WS_DECB4+idx] = decbih[j] + decbhh[j];
  }
  for (int idx = tid0; idx < 64*64; idx += stride) {
    int e = idx >> 6, l = idx & 63;
    ws[WS_W1HC2 + (e*64+l)*2 + 0] = w1[l*192 + e];
    ws[WS_W1HC2 + (e*64+l)*2 + 1] = w1[l*192 + 64 + e];
    ws[WS_W1XT  + idx]            = w1[l*192 + 128 + e];
  }
}

// R=1: one batch row per wave. Register demand ~55 -> fits the 64-VGPR class
// (gfx950 wave-slot pool ~256 VGPR/SIMD; 65..128 VGPR all alias to 2 waves/SIMD,
// <=64 gives 4 waves/SIMD). NO __shared__, no bias hoists.
__global__ __launch_bounds__(256, 4) void darnn_kernel(
    const float* __restrict__ x, const float* __restrict__ y_hist,
    const float* __restrict__ h0e, const float* __restrict__ c0e,
    const float* __restrict__ h0d, const float* __restrict__ c0d,
    const float* __restrict__ enc_attn_w,
    const float* __restrict__ dec_attn_b1, const float* __restrict__ dec_attn_w2,
    const float* __restrict__ dec_attn_b2,
    const float* __restrict__ fc_w, const float* __restrict__ fc_b,
    const float* __restrict__ fcout_w, const float* __restrict__ fcout_b,
    const float* __restrict__ ws, float* __restrict__ out)
{
  const int l  = threadIdx.x & 63;
  const int wv = threadIdx.x >> 6;
  const int brow = blockIdx.x * 4 + wv;

  const float* encW4 = ws + WS_ENCW4;
  const float* decW4 = ws + WS_DECW4;
  const float* xb = x + (size_t)brow*(L_*D_);
  const float* yb = y_hist + (size_t)brow*(L_*OUT_);

  float h = h0e[brow*64+l];
  float c = c0e[brow*64+l];

  // Encoder input attention: at = softmax_d(score_x) (h/c/bias terms cancel in softmax)
  float at0, at1;
  {
    float s0=0.f, s1=0.f;
    #pragma unroll
    for (int t=0;t<L_;++t){
      float wx = enc_attn_w[2*H_ + t];          // wave-uniform -> SGPR
      s0 += xb[t*D_+l]*wx;
      s1 += xb[t*D_+64+l]*wx;
    }
    float m = fmaxf(s0,s1);
    for (int o=32;o;o>>=1) m = fmaxf(m, __shfl_xor(m,o));
    float e0=__expf(s0-m), e1=__expf(s1-m);
    float ss=e0+e1;
    for (int o=32;o;o>>=1) ss += __shfl_xor(ss,o);
    float inv = 1.f/ss;
    at0=e0*inv; at1=e1*inv;
  }

  // ---------------- Encoder ----------------
  float xe[L_];          // encoder hidden states, lane l holds element l
  for (int t=0;t<L_;++t){
    float wi0 = at0*xb[t*D_+l];
    float wi1 = at1*xb[t*D_+64+l];
    float4 bs = *(const float4*)(ws + WS_ENCB4 + l*4);
    float a0=bs.x, a1=bs.y, a2=bs.z, a3=bs.w;
    #pragma unroll 4
    for (int d=0; d<64; ++d){
      float4 w = *(const float4*)(encW4 + (d*64+l)*4);
      float v = bcast(wi0, d);
      a0+=v*w.x; a1+=v*w.y; a2+=v*w.z; a3+=v*w.w;
    }
    #pragma unroll 4
    for (int d=0; d<64; ++d){
      float4 w = *(const float4*)(encW4 + ((64+d)*64+l)*4);
      float v = bcast(wi1, d);
      a0+=v*w.x; a1+=v*w.y; a2+=v*w.z; a3+=v*w.w;
    }
    #pragma unroll 4
    for (int e=0;e<64;++e){
      float4 w = *(const float4*)(encW4 + ((128+e)*64+l)*4);
      float v = bcast(h, e);
      a0+=v*w.x; a1+=v*w.y; a2+=v*w.z; a3+=v*w.w;
    }
    float ig=sigmf(a0), fg=sigmf(a1), gg=tanhf_(a2), og=sigmf(a3);
    c=fg*c+ig*gg;
    h=og*tanhf_(c);
    xe[t]=h;
  }

  // pre[lt] = sum_e xe[lt](e) * W1x[l][e]   (e-outer, weight loaded once per e)
  float pre[L_];
  #pragma unroll
  for (int lt=0;lt<L_;++lt) pre[lt]=0.f;
  #pragma unroll 2
  for (int e=0;e<64;++e){
    float w = ws[WS_W1XT + e*64+l];
    #pragma unroll
    for (int lt=0;lt<L_;++lt)
      pre[lt] += bcast(xe[lt], e) * w;
  }

  // ---------------- Decoder ----------------
  h = h0d[brow*64+l];
  c = c0d[brow*64+l];
  float ctx = 0.f;

  for (int t=0;t<L_;++t){
    // vb[l] = b1[l] + sum_e h(e) W1h[l][e] + c(e) W1c[l][e]
    float vb = dec_attn_b1[l];
    #pragma unroll 8
    for (int e=0;e<64;++e){
      float2 w = *(const float2*)(ws + WS_W1HC2 + (e*64+l)*2);
      vb += bcast(h,e)*w.x + bcast(c,e)*w.y;
    }
    // scores -> softmax over L -> ctx
    float w2l = dec_attn_w2[l];
    float sc[L_];
    #pragma unroll
    for (int lt=0;lt<L_;++lt){
      float z = tanhf_(pre[lt]+vb);
      float p = z*w2l;
      for (int o=32;o;o>>=1) p += __shfl_xor(p,o);
      sc[lt]=p;                       // + b2 constant: cancels in softmax
    }
    float mx=sc[0];
    #pragma unroll
    for (int lt=1;lt<L_;++lt) mx=fmaxf(mx,sc[lt]);
    float ssum=0.f;
    #pragma unroll
    for (int lt=0;lt<L_;++lt){ sc[lt]=__expf(sc[lt]-mx); ssum+=sc[lt]; }
    float inv=1.f/ssum;
    float cx=0.f;
    #pragma unroll
    for (int lt=0;lt<L_;++lt) cx += sc[lt]*xe[lt];
    ctx=cx*inv;

    // y_tilde[o] = fc_b[o] + sum_e ctx(e) fc_w[o][e] + sum_j y_t[j] fc_w[o][64+j]
    float yt[OUT_];
    #pragma unroll
    for (int o2=0;o2<OUT_;++o2){
      float p = ctx*fc_w[o2*69+l];
      for (int o=32;o;o>>=1) p += __shfl_xor(p,o);
      p += fc_b[o2];                                 // uniform -> SGPR
      #pragma unroll
      for (int j=0;j<OUT_;++j)
        p += yb[t*OUT_+j]*fc_w[o2*69+64+j];          // uniform*uniform -> SALU-friendly
      yt[o2]=p;
    }
    // gates
    float4 bs = *(const float4*)(ws + WS_DECB4 + l*4);
    float a0=bs.x, a1=bs.y, a2=bs.z, a3=bs.w;
    #pragma unroll
    for (int k=0;k<OUT_;++k){
      float4 w = *(const float4*)(decW4 + (k*64+l)*4);
      float v = yt[k];
      a0+=v*w.x; a1+=v*w.y; a2+=v*w.z; a3+=v*w.w;
    }
    #pragma unroll 4
    for (int e=0;e<64;++e){
      float4 w = *(const float4*)(decW4 + ((5+e)*64+l)*4);
      float v = bcast(h,e);
      a0+=v*w.x; a1+=v*w.y; a2+=v*w.z; a3+=v*w.w;
    }
    float ig=sigmf(a0), fg=sigmf(a1), gg=tanhf_(a2), og=sigmf(a3);
    c=fg*c+ig*gg;
    h=og*tanhf_(c);
  }

  // out[b][o] = fcout_b[o] + sum_e h(e) fcout_w[o][e] + ctx(e) fcout_w[o][64+e]
  #pragma unroll
  for (int o2=0;o2<OUT_;++o2){
    float p = h*fcout_w[o2*128+l] + ctx*fcout_w[o2*128+64+l];
    for (int o=32;o;o>>=1) p += __shfl_xor(p,o);
    if (l==o2) out[(size_t)brow*OUT_+o2] = p + fcout_b[o2];
  }
}

extern "C" void kernel_launch(void* const* d_in, const int* in_sizes, int n_in,
                              void* d_out, int out_size, void* d_ws, size_t ws_size,
                              hipStream_t stream) {
  const float* x          = (const float*)d_in[0];
  const float* y_hist     = (const float*)d_in[1];
  const float* h0_enc     = (const float*)d_in[2];
  const float* c0_enc     = (const float*)d_in[3];
  const float* h0_dec     = (const float*)d_in[4];
  const float* c0_dec     = (const float*)d_in[5];
  const float* enc_attn_w = (const float*)d_in[6];
  const float* enc_Wih    = (const float*)d_in[8];
  const float* enc_Whh    = (const float*)d_in[9];
  const float* enc_bih    = (const float*)d_in[10];
  const float* enc_bhh    = (const float*)d_in[11];
  const float* dec_attn_w1= (const float*)d_in[12];
  const float* dec_attn_b1= (const float*)d_in[13];
  const float* dec_attn_w2= (const float*)d_in[14];
  const float* dec_attn_b2= (const float*)d_in[15];
  const float* dec_Wih    = (const float*)d_in[16];
  const float* dec_Whh    = (const float*)d_in[17];
  const float* dec_bih    = (const float*)d_in[18];
  const float* dec_bhh    = (const float*)d_in[19];
  const float* fc_w       = (const float*)d_in[20];
  const float* fc_b       = (const float*)d_in[21];
  const float* fcout_w    = (const float*)d_in[22];
  const float* fcout_b    = (const float*)d_in[23];
  float* ws = (float*)d_ws;
  float* out = (float*)d_out;

  hipLaunchKernelGGL(prep_kernel, dim3(128), dim3(256), 0, stream,
                     enc_Wih, enc_Whh, enc_bih, enc_bhh,
                     dec_Wih, dec_Whh, dec_bih, dec_bhh,
                     dec_attn_w1, ws);
  hipLaunchKernelGGL(darnn_kernel, dim3(B_/4), dim3(256), 0, stream,
                     x, y_hist, h0_enc, c0_enc, h0_dec, c0_dec,
                     enc_attn_w, dec_attn_b1, dec_attn_w2, dec_attn_b2,
                     fc_w, fc_b, fcout_w, fcout_b, ws, out);
}

// Round 7
// 426.779 us; speedup vs baseline: 2.0435x; 2.0435x over previous
//
#include <hip/hip_runtime.h>

// Problem constants
#define B_  8192
#define L_  10
#define D_  128
#define H_  64
#define OUT_ 5

typedef _Float16 h2 __attribute__((ext_vector_type(2)));
typedef unsigned int uint;

// ws dword layout:
#define WS_ENCPK   0        // [kp<96][l]: uint4, dword q = half2(W[q*64+l][2kp], [2kp+1]); k<128: Wih, else Whh
#define WS_ENCB    24576    // 256 floats: [l][q] = bih+bhh
#define WS_DECY    24832    // [k<5][l]: float4 fp32 (dec Wih columns)
#define WS_DECPK   26112    // [ep<32][l]: uint4, half2(decWhh[q*64+l][2ep], [2ep+1])
#define WS_DECB    34304    // 256 floats
#define WS_W1HCP   34560    // [ep<32][l]: uint2 {half2 W1h pair, half2 W1c pair}
#define WS_W1XP    38656    // [ep<32][l]: uint half2 W1x pair

__device__ __forceinline__ float sigmf(float x){ return 1.f/(1.f+__expf(-x)); }
__device__ __forceinline__ float tanhf_(float x){ return 1.f - 2.f/(1.f+__expf(2.f*x)); }
__device__ __forceinline__ float bcast(float v, int lane){
  return __uint_as_float(__builtin_amdgcn_readlane(__float_as_uint(v), lane));
}
__device__ __forceinline__ uint bcastu(uint v, int lane){
  return (uint)__builtin_amdgcn_readlane((int)v, lane);
}
__device__ __forceinline__ float dot2(uint w, uint a, float acc){
  return __builtin_amdgcn_fdot2(__builtin_bit_cast(h2, w), __builtin_bit_cast(h2, a), acc, false);
}
__device__ __forceinline__ uint pack_rtz(float a, float b){
  return __builtin_bit_cast(uint, __builtin_amdgcn_cvt_pkrtz(a, b));
}
// RTN pack for prep (better weight precision)
__device__ __forceinline__ uint pack_rtn(float a, float b){
  h2 v; v.x = (_Float16)a; v.y = (_Float16)b;
  return __builtin_bit_cast(uint, v);
}

__global__ void prep_kernel(const float* __restrict__ encWih, const float* __restrict__ encWhh,
                            const float* __restrict__ encbih, const float* __restrict__ encbhh,
                            const float* __restrict__ decWih, const float* __restrict__ decWhh,
                            const float* __restrict__ decbih, const float* __restrict__ decbhh,
                            const float* __restrict__ w1, float* __restrict__ wsf)
{
  uint* ws = (uint*)wsf;
  int stride = gridDim.x * blockDim.x;
  int tid0 = blockIdx.x * blockDim.x + threadIdx.x;

  // enc packed panels: 96 k-pairs
  for (int idx = tid0; idx < 96*64; idx += stride) {
    int kp = idx >> 6, l = idx & 63;
    uint4 o;
    uint* op = (uint*)&o;
    #pragma unroll
    for (int q=0;q<4;++q){
      int j = q*64 + l;
      int k0 = 2*kp, k1 = 2*kp+1;
      float a = (k0 < 128) ? encWih[j*128 + k0] : encWhh[j*64 + (k0-128)];
      float b = (k1 < 128) ? encWih[j*128 + k1] : encWhh[j*64 + (k1-128)];
      op[q] = pack_rtn(a,b);
    }
    ((uint4*)(ws + WS_ENCPK))[idx] = o;
  }
  for (int idx = tid0; idx < 256; idx += stride) {
    int l = idx >> 2, q = idx & 3, j = q*64+l;
    wsf[WS_ENCB+idx] = encbih[j] + encbhh[j];
  }
  // dec y-part fp32
  for (int idx = tid0; idx < 5*64; idx += stride) {
    int k = idx >> 6, l = idx & 63;
    float4 o;
    o.x = decWih[(0*64+l)*5 + k];
    o.y = decWih[(1*64+l)*5 + k];
    o.z = decWih[(2*64+l)*5 + k];
    o.w = decWih[(3*64+l)*5 + k];
    ((float4*)(wsf + WS_DECY))[idx] = o;
  }
  // dec h-part packed: 32 e-pairs
  for (int idx = tid0; idx < 32*64; idx += stride) {
    int ep = idx >> 6, l = idx & 63;
    uint4 o; uint* op = (uint*)&o;
    #pragma unroll
    for (int q=0;q<4;++q){
      int j = q*64 + l;
      op[q] = pack_rtn(decWhh[j*64 + 2*ep], decWhh[j*64 + 2*ep+1]);
    }
    ((uint4*)(ws + WS_DECPK))[idx] = o;
  }
  for (int idx = tid0; idx < 256; idx += stride) {
    int l = idx >> 2, q = idx & 3, j = q*64+l;
    wsf[WS_DECB+idx] = decbih[j] + decbhh[j];
  }
  // W1h/W1c pairs
  for (int idx = tid0; idx < 32*64; idx += stride) {
    int ep = idx >> 6, l = idx & 63;
    uint2 o;
    o.x = pack_rtn(w1[l*192 + 2*ep],      w1[l*192 + 2*ep+1]);
    o.y = pack_rtn(w1[l*192 + 64 + 2*ep], w1[l*192 + 64 + 2*ep+1]);
    ((uint2*)(ws + WS_W1HCP))[idx] = o;
  }
  // W1x pairs
  for (int idx = tid0; idx < 32*64; idx += stride) {
    int ep = idx >> 6, l = idx & 63;
    ws[WS_W1XP + idx] = pack_rtn(w1[l*192 + 128 + 2*ep], w1[l*192 + 128 + 2*ep+1]);
  }
}

#define R 2   // batch rows per wave (grid = 1024 blocks)

__global__ __launch_bounds__(256, 2) void darnn_kernel(
    const float* __restrict__ x, const float* __restrict__ y_hist,
    const float* __restrict__ h0e, const float* __restrict__ c0e,
    const float* __restrict__ h0d, const float* __restrict__ c0d,
    const float* __restrict__ enc_attn_w,
    const float* __restrict__ dec_attn_b1, const float* __restrict__ dec_attn_w2,
    const float* __restrict__ dec_attn_b2,
    const float* __restrict__ fc_w, const float* __restrict__ fc_b,
    const float* __restrict__ fcout_w, const float* __restrict__ fcout_b,
    const float* __restrict__ ws, float* __restrict__ out)
{
  const int l  = threadIdx.x & 63;
  const int wv = threadIdx.x >> 6;
  const int brow = blockIdx.x * (4*R) + wv*R;
  const int m2 = 2*(l&31);

  const uint4*  encPk = (const uint4*)((const uint*)ws + WS_ENCPK);
  const float4* decY  = (const float4*)(ws + WS_DECY);
  const uint4*  decPk = (const uint4*)((const uint*)ws + WS_DECPK);
  const uint2*  w1hcp = (const uint2*)((const uint*)ws + WS_W1HCP);
  const uint*   w1xp  = (const uint*)ws + WS_W1XP;

  float h[R], c[R];
  #pragma unroll
  for (int r=0;r<R;++r){
    h[r]=h0e[(brow+r)*64+l];
    c[r]=c0e[(brow+r)*64+l];
  }

  // Encoder input attention: at = softmax_d(score_x) (h/c/bias cancel in softmax)
  float at0[R], at1[R];
  {
    float wxv[L_];
    #pragma unroll
    for (int t=0;t<L_;++t) wxv[t]=enc_attn_w[2*H_ + t];
    #pragma unroll
    for (int r=0;r<R;++r){
      const float* xb = x + (size_t)(brow+r)*(L_*D_);
      float s0=0.f,s1=0.f;
      #pragma unroll
      for (int t=0;t<L_;++t){
        s0 += xb[t*D_+l]*wxv[t];
        s1 += xb[t*D_+64+l]*wxv[t];
      }
      float m = fmaxf(s0,s1);
      for (int o=32;o;o>>=1) m = fmaxf(m, __shfl_xor(m,o));
      float e0=__expf(s0-m), e1=__expf(s1-m);
      float ss=e0+e1;
      for (int o=32;o;o>>=1) ss += __shfl_xor(ss,o);
      float inv = 1.f/ss;
      at0[r]=e0*inv; at1[r]=e1*inv;
    }
  }

  // hoisted attention-pair values (t-invariant): at for elems m2, m2+1 of each half
  float at0a[R], at0b[R], at1a[R], at1b[R];
  #pragma unroll
  for (int r=0;r<R;++r){
    at0a[r]=__shfl(at0[r], m2);  at0b[r]=__shfl(at0[r], m2+1);
    at1a[r]=__shfl(at1[r], m2);  at1b[r]=__shfl(at1[r], m2+1);
  }

  // ---------------- Encoder ----------------
  float xe[R][L_];
  const float* xb0 = x + (size_t)(brow+0)*(L_*D_);
  const float* xb1 = x + (size_t)(brow+1)*(L_*D_);

  for (int t=0;t<L_;++t){
    // build packed act pairs: lanes 0..31 hold pairs 0..31 (upper lanes duplicate)
    uint wi0p[R], wi1p[R], hp[R];
    {
      float2 xp00 = *(const float2*)(xb0 + t*D_ + m2);
      float2 xp01 = *(const float2*)(xb0 + t*D_ + 64 + m2);
      float2 xp10 = *(const float2*)(xb1 + t*D_ + m2);
      float2 xp11 = *(const float2*)(xb1 + t*D_ + 64 + m2);
      wi0p[0]=pack_rtz(at0a[0]*xp00.x, at0b[0]*xp00.y);
      wi1p[0]=pack_rtz(at1a[0]*xp01.x, at1b[0]*xp01.y);
      wi0p[1]=pack_rtz(at0a[1]*xp10.x, at0b[1]*xp10.y);
      wi1p[1]=pack_rtz(at1a[1]*xp11.x, at1b[1]*xp11.y);
      #pragma unroll
      for (int r=0;r<R;++r)
        hp[r]=pack_rtz(__shfl(h[r],m2), __shfl(h[r],m2+1));
    }
    float4 bs = *(const float4*)(ws + WS_ENCB + l*4);
    float a0[R],a1[R],a2[R],a3[R];
    #pragma unroll
    for (int r=0;r<R;++r){ a0[r]=bs.x;a1[r]=bs.y;a2[r]=bs.z;a3[r]=bs.w; }
    #pragma unroll 4
    for (int kp=0; kp<32; ++kp){
      uint4 w = encPk[kp*64+l];
      #pragma unroll
      for (int r=0;r<R;++r){
        uint u = bcastu(wi0p[r], kp);
        a0[r]=dot2(w.x,u,a0[r]); a1[r]=dot2(w.y,u,a1[r]);
        a2[r]=dot2(w.z,u,a2[r]); a3[r]=dot2(w.w,u,a3[r]);
      }
    }
    #pragma unroll 4
    for (int kp=0; kp<32; ++kp){
      uint4 w = encPk[(32+kp)*64+l];
      #pragma unroll
      for (int r=0;r<R;++r){
        uint u = bcastu(wi1p[r], kp);
        a0[r]=dot2(w.x,u,a0[r]); a1[r]=dot2(w.y,u,a1[r]);
        a2[r]=dot2(w.z,u,a2[r]); a3[r]=dot2(w.w,u,a3[r]);
      }
    }
    #pragma unroll 4
    for (int kp=0; kp<32; ++kp){
      uint4 w = encPk[(64+kp)*64+l];
      #pragma unroll
      for (int r=0;r<R;++r){
        uint u = bcastu(hp[r], kp);
        a0[r]=dot2(w.x,u,a0[r]); a1[r]=dot2(w.y,u,a1[r]);
        a2[r]=dot2(w.z,u,a2[r]); a3[r]=dot2(w.w,u,a3[r]);
      }
    }
    #pragma unroll
    for (int r=0;r<R;++r){
      float ig=sigmf(a0[r]), fg=sigmf(a1[r]), gg=tanhf_(a2[r]), og=sigmf(a3[r]);
      c[r]=fg*c[r]+ig*gg;
      h[r]=og*tanhf_(c[r]);
      xe[r][t]=h[r];
    }
  }

  // pre[r][lt] = sum_e xe[r][lt](e) * W1x[l][e]  via packed pairs
  float pre[R][L_];
  {
    uint xep[R][L_];
    #pragma unroll
    for (int r=0;r<R;++r)
      #pragma unroll
      for (int lt=0;lt<L_;++lt){
        xep[r][lt]=pack_rtz(__shfl(xe[r][lt],m2), __shfl(xe[r][lt],m2+1));
        pre[r][lt]=0.f;
      }
    #pragma unroll 2
    for (int ep=0;ep<32;++ep){
      uint w = w1xp[ep*64+l];
      #pragma unroll
      for (int r=0;r<R;++r)
        #pragma unroll
        for (int lt=0;lt<L_;++lt)
          pre[r][lt] = dot2(w, bcastu(xep[r][lt], ep), pre[r][lt]);
    }
  }

  // ---------------- Decoder ----------------
  #pragma unroll
  for (int r=0;r<R;++r){
    h[r]=h0d[(brow+r)*64+l];
    c[r]=c0d[(brow+r)*64+l];
  }
  float b1l = dec_attn_b1[l];
  float w2l = dec_attn_w2[l];
  float ctx[R];
  #pragma unroll
  for (int r=0;r<R;++r) ctx[r]=0.f;

  const float* yb0 = y_hist + (size_t)(brow+0)*(L_*OUT_);
  const float* yb1 = y_hist + (size_t)(brow+1)*(L_*OUT_);

  for (int t=0;t<L_;++t){
    // packed h,c pairs for this step
    uint hp[R], cp[R];
    #pragma unroll
    for (int r=0;r<R;++r){
      hp[r]=pack_rtz(__shfl(h[r],m2), __shfl(h[r],m2+1));
      cp[r]=pack_rtz(__shfl(c[r],m2), __shfl(c[r],m2+1));
    }
    // vb[l] = b1[l] + sum_e h(e)W1h[l][e] + c(e)W1c[l][e]
    float vb[R];
    #pragma unroll
    for (int r=0;r<R;++r) vb[r]=b1l;
    #pragma unroll 4
    for (int ep=0;ep<32;++ep){
      uint2 w = w1hcp[ep*64+l];
      #pragma unroll
      for (int r=0;r<R;++r){
        vb[r]=dot2(w.x, bcastu(hp[r],ep), vb[r]);
        vb[r]=dot2(w.y, bcastu(cp[r],ep), vb[r]);
      }
    }
    // scores -> softmax over L -> ctx
    float yt[R][OUT_];
    #pragma unroll
    for (int r=0;r<R;++r){
      float sc[L_];
      #pragma unroll
      for (int lt=0;lt<L_;++lt){
        float z = tanhf_(pre[r][lt]+vb[r]);
        float p = z*w2l;
        for (int o=32;o;o>>=1) p += __shfl_xor(p,o);
        sc[lt]=p;
      }
      float mx=sc[0];
      #pragma unroll
      for (int lt=1;lt<L_;++lt) mx=fmaxf(mx,sc[lt]);
      float ssum=0.f;
      #pragma unroll
      for (int lt=0;lt<L_;++lt){ sc[lt]=__expf(sc[lt]-mx); ssum+=sc[lt]; }
      float inv=1.f/ssum;
      float cx=0.f;
      #pragma unroll
      for (int lt=0;lt<L_;++lt) cx += sc[lt]*xe[r][lt];
      ctx[r]=cx*inv;
    }
    // y_tilde
    #pragma unroll
    for (int r=0;r<R;++r){
      const float* yb = (r==0)?yb0:yb1;
      float yin[OUT_];
      #pragma unroll
      for (int j=0;j<OUT_;++j) yin[j]=yb[t*OUT_+j];
      #pragma unroll
      for (int o2=0;o2<OUT_;++o2){
        float p = ctx[r]*fc_w[o2*69+l];
        for (int o=32;o;o>>=1) p += __shfl_xor(p,o);
        p += fc_b[o2];
        #pragma unroll
        for (int j=0;j<OUT_;++j) p += yin[j]*fc_w[o2*69+64+j];
        yt[r][o2]=p;
      }
    }
    // gates: y part fp32, h part packed dot2
    float4 bs = *(const float4*)(ws + WS_DECB + l*4);
    float a0[R],a1[R],a2[R],a3[R];
    #pragma unroll
    for (int r=0;r<R;++r){ a0[r]=bs.x;a1[r]=bs.y;a2[r]=bs.z;a3[r]=bs.w; }
    #pragma unroll
    for (int k=0;k<OUT_;++k){
      float4 w = decY[k*64+l];
      #pragma unroll
      for (int r=0;r<R;++r){
        float v = yt[r][k];
        a0[r]+=v*w.x;a1[r]+=v*w.y;a2[r]+=v*w.z;a3[r]+=v*w.w;
      }
    }
    #pragma unroll 4
    for (int ep=0;ep<32;++ep){
      uint4 w = decPk[ep*64+l];
      #pragma unroll
      for (int r=0;r<R;++r){
        uint u = bcastu(hp[r], ep);
        a0[r]=dot2(w.x,u,a0[r]); a1[r]=dot2(w.y,u,a1[r]);
        a2[r]=dot2(w.z,u,a2[r]); a3[r]=dot2(w.w,u,a3[r]);
      }
    }
    #pragma unroll
    for (int r=0;r<R;++r){
      float ig=sigmf(a0[r]), fg=sigmf(a1[r]), gg=tanhf_(a2[r]), og=sigmf(a3[r]);
      c[r]=fg*c[r]+ig*gg;
      h[r]=og*tanhf_(c[r]);
    }
  }

  // out epilogue
  #pragma unroll
  for (int o2=0;o2<OUT_;++o2){
    float wa=fcout_w[o2*128+l];
    float wb=fcout_w[o2*128+64+l];
    float fb=fcout_b[o2];
    #pragma unroll
    for (int r=0;r<R;++r){
      float p = h[r]*wa + ctx[r]*wb;
      for (int o=32;o;o>>=1) p += __shfl_xor(p,o);
      if (l==o2) out[(size_t)(brow+r)*OUT_+o2] = p+fb;
    }
  }
}

extern "C" void kernel_launch(void* const* d_in, const int* in_sizes, int n_in,
                              void* d_out, int out_size, void* d_ws, size_t ws_size,
                              hipStream_t stream) {
  const float* x          = (const float*)d_in[0];
  const float* y_hist     = (const float*)d_in[1];
  const float* h0_enc     = (const float*)d_in[2];
  const float* c0_enc     = (const float*)d_in[3];
  const float* h0_dec     = (const float*)d_in[4];
  const float* c0_dec     = (const float*)d_in[5];
  const float* enc_attn_w = (const float*)d_in[6];
  const float* enc_Wih    = (const float*)d_in[8];
  const float* enc_Whh    = (const float*)d_in[9];
  const float* enc_bih    = (const float*)d_in[10];
  const float* enc_bhh    = (const float*)d_in[11];
  const float* dec_attn_w1= (const float*)d_in[12];
  const float* dec_attn_b1= (const float*)d_in[13];
  const float* dec_attn_w2= (const float*)d_in[14];
  const float* dec_attn_b2= (const float*)d_in[15];
  const float* dec_Wih    = (const float*)d_in[16];
  const float* dec_Whh    = (const float*)d_in[17];
  const float* dec_bih    = (const float*)d_in[18];
  const float* dec_bhh    = (const float*)d_in[19];
  const float* fc_w       = (const float*)d_in[20];
  const float* fc_b       = (const float*)d_in[21];
  const float* fcout_w    = (const float*)d_in[22];
  const float* fcout_b    = (const float*)d_in[23];
  float* ws = (float*)d_ws;
  float* out = (float*)d_out;

  hipLaunchKernelGGL(prep_kernel, dim3(128), dim3(256), 0, stream,
                     enc_Wih, enc_Whh, enc_bih, enc_bhh,
                     dec_Wih, dec_Whh, dec_bih, dec_bhh,
                     dec_attn_w1, ws);
  hipLaunchKernelGGL(darnn_kernel, dim3(B_/(4*R)), dim3(256), 0, stream,
                     x, y_hist, h0_enc, c0_enc, h0_dec, c0_dec,
                     enc_attn_w, dec_attn_b1, dec_attn_w2, dec_attn_b2,
                     fc_w, fc_b, fcout_w, fcout_b, ws, out);
}